// Round 8
// baseline (409.519 us; speedup 1.0000x reference)
//
#include <hip/hip_runtime.h>

// Fused attention fwd: R = softmax(Q K^T / sqrt(D)) V, plus attn weights P.
// B=16, LQ=LK=2048, D=128, fp32 in/out.
//
// Round 11 = round 10 resubmitted verbatim (r10 bench died on container
// acquisition, not on the kernel; audit found no hang/OOB candidate).
//
// Round 10 rationale: r9 decoded: dur_us = harness tax (~181us d_ws fill +
// ~45us out memset) + our kernels. Our kernels ~162us (attn ~140, prepack
// ~20); the occupancy fix worked once spills were gone. The d_ws fill also
// proves NT writes sustain 6.3 TB/s -> P-write floor ~43us; attn has 2x
// headroom. THIS ROUND: evict pass 1 (16 of 48 barrier-locked iters, ~45us,
// and a 64x-redundant K re-stage) from the occupancy-constrained attn
// kernel into prepack, where block (b,kt) already holds the packed K tile:
//  - prepack: kf hoisted to regs once (no barriers, no re-staging), Q[b]
//    streamed from L2, rowsum partials to Psum[b][kt][q] in d_ws via PLAIN
//    stores (no atomics, no zeroing -- every slot overwritten).
//  - attn: pass 2 only; rinv = 1/sum of 32 L2-hot partials, loaded at start.
// Kept from r9: bf16 LDS-image prepack (XOR-swizzled, linear gll dest),
// global_load_lds staging (zero staging VGPRs -> no spills at 4 blocks/CU),
// swapped QK^T (per-lane scalar softmax), lgkm-only barriers, counted
// vmcnt(2) (never 0 mid-loop), full-line NT P stores, batch-major grid.

#define NB  16
#define SLQ 2048
#define SLK 2048
#define DH  128
#define BQ  32
#define BK  64

typedef __bf16 bf16;
typedef bf16  bf16x8 __attribute__((ext_vector_type(8)));
typedef bf16  bf16x4 __attribute__((ext_vector_type(4)));
typedef float f32x4  __attribute__((ext_vector_type(4)));
typedef float f32x16 __attribute__((ext_vector_type(16)));

#define SCALE 0.088388347648318447f  // 1/sqrt(128)

__device__ __forceinline__ f32x16 mfma32(bf16x8 a, bf16x8 b, f32x16 c) {
    return __builtin_amdgcn_mfma_f32_32x32x16_bf16(a, b, c, 0, 0, 0);
}

__device__ __forceinline__ bf16x8 cvt8(f32x4 v0, f32x4 v1) {
    bf16x8 r;
    r[0] = (bf16)v0[0]; r[1] = (bf16)v0[1]; r[2] = (bf16)v0[2]; r[3] = (bf16)v0[3];
    r[4] = (bf16)v1[0]; r[5] = (bf16)v1[1]; r[6] = (bf16)v1[2]; r[7] = (bf16)v1[3];
    return r;
}

__device__ __forceinline__ bf16x8 cvt8s(f32x4 v0, f32x4 v1, float s) {
    bf16x8 r;
    r[0] = (bf16)(v0[0] * s); r[1] = (bf16)(v0[1] * s);
    r[2] = (bf16)(v0[2] * s); r[3] = (bf16)(v0[3] * s);
    r[4] = (bf16)(v1[0] * s); r[5] = (bf16)(v1[1] * s);
    r[6] = (bf16)(v1[3 - 3 + 2] * s); r[7] = (bf16)(v1[3] * s);
    return r;
}

// Workgroup barrier waiting only on LDS ops (lgkmcnt), NOT vmcnt.
__device__ __forceinline__ void barrier_lgkm() {
    asm volatile("s_waitcnt lgkmcnt(0)" ::: "memory");
    __builtin_amdgcn_s_barrier();
    asm volatile("" ::: "memory");
}

// async global->LDS, 16B per lane. LDS dest = wave-uniform base + lane*16.
__device__ __forceinline__ void gll16(const void* g, void* l) {
    __builtin_amdgcn_global_load_lds(
        (const __attribute__((address_space(1))) void*)g,
        (__attribute__((address_space(3))) void*)l, 16, 0, 0);
}

// ---------------- pre-pass: pack images + rowsum partials ------------------
// K image tile (per (b,kt), 16KB): content[row*256 + ((col*2)^((row&7)<<4))]
//   = bf16(K[b][kt*64+row][col]), row=key 0..63, col=d 0..127.
// V image tile (16KB): content[d*128 + ((k*2)^((d&7)<<4))]
//   = bf16(V[b][kt*64+k][d]), d 0..127, k 0..63.
// Psum[(b*32+kt)*2048 + q] = sum_{k in tile} exp(Q[q]·K[k]*SCALE) (f32).
__global__ __launch_bounds__(256)
void prepack(const float* __restrict__ Q, const float* __restrict__ K,
             const float* __restrict__ V, bf16* __restrict__ Kimg,
             bf16* __restrict__ Vimg, float* __restrict__ Psum) {
    const int b = blockIdx.x, kt = blockIdx.y;
    const int tid = threadIdx.x;
    const int wave = tid >> 6, lane = tid & 63;
    const int n31 = lane & 31, h = lane >> 5;
    const float* Kb = K + ((size_t)b * SLK + (size_t)kt * 64) * DH;
    const float* Vb = V + ((size_t)b * SLK + (size_t)kt * 64) * DH;
    char* kout = (char*)(Kimg) + ((size_t)b * 32 + kt) * 16384;
    char* vout = (char*)(Vimg) + ((size_t)b * 32 + kt) * 16384;

    __shared__ __align__(16) char KsL[16384];      // K image mirror
    __shared__ float Vf[64][132];                  // V f32 stage (528B rows)

    // K: coalesced img writes (global + LDS mirror); col via XOR involution
#pragma unroll
    for (int i = 0; i < 4; ++i) {
        int ib  = (tid + i * 256) * 16;
        int row = ib >> 8;
        int src = (ib & 255) ^ ((row & 7) << 4);
        int col = src >> 1;
        const float* kp = Kb + (size_t)row * DH + col;
        bf16x8 w = cvt8(*(const f32x4*)kp, *(const f32x4*)(kp + 4));
        *(bf16x8*)(kout + ib) = w;
        *(bf16x8*)(KsL + ib)  = w;
    }

    // V: coalesced f32 stage into LDS, then transposed swizzled img writes
#pragma unroll
    for (int i = 0; i < 8; ++i) {
        int u = tid + i * 256;
        int k = u >> 5, c4 = (u & 31) * 4;
        *(f32x4*)&Vf[k][c4] = *(const f32x4*)(Vb + (size_t)k * DH + c4);
    }
    __syncthreads();                               // Vf + KsL visible
#pragma unroll
    for (int i = 0; i < 4; ++i) {
        int ib = (tid + i * 256) * 16;
        int d  = ib >> 7;
        int src = (ib & 127) ^ ((d & 7) << 4);
        int k0 = src >> 1;
        bf16x8 w;
#pragma unroll
        for (int j = 0; j < 8; ++j) w[j] = (bf16)Vf[k0 + j][d];
        *(bf16x8*)(vout + ib) = w;
    }

    // rowsum QK: kf hoisted once; Q streamed; no barriers, no re-staging.
    bf16x8 kf0[8], kf1[8];
    {
        const char* p0 = KsL + (size_t)(n31) * 256;
        const char* p1 = KsL + (size_t)(32 + n31) * 256;
        const int s0 = (n31 & 7) << 4, s1 = ((32 + n31) & 7) << 4;
#pragma unroll
        for (int kk = 0; kk < 8; ++kk) {
            kf0[kk] = *(const bf16x8*)(p0 + ((kk * 32 + 16 * h) ^ s0));
            kf1[kk] = *(const bf16x8*)(p1 + ((kk * 32 + 16 * h) ^ s1));
        }
    }
    const float* Qb = Q + (size_t)b * SLQ * DH;
    float* Pout = Psum + ((size_t)b * 32 + kt) * SLQ;
    for (int qg = 0; qg < 16; ++qg) {
        const int q0 = wave * 512 + qg * 32;
        const float* qp = Qb + (size_t)(q0 + n31) * DH + h * 8;
        bf16x8 aq[8];
#pragma unroll
        for (int kk = 0; kk < 8; ++kk)
            aq[kk] = cvt8s(*(const f32x4*)(qp + kk * 16),
                           *(const f32x4*)(qp + kk * 16 + 4), SCALE);
        f32x16 c0 = (f32x16)0.0f, c1 = (f32x16)0.0f;
#pragma unroll
        for (int kk = 0; kk < 8; ++kk) {
            c0 = mfma32(kf0[kk], aq[kk], c0);
            c1 = mfma32(kf1[kk], aq[kk], c1);
        }
        float ps = 0.f;
#pragma unroll
        for (int r = 0; r < 16; ++r) ps += __expf(c0[r]) + __expf(c1[r]);
        ps += __shfl_xor(ps, 32);                  // merge h key-halves
        if (lane < 32) Pout[q0 + n31] = ps;        // plain store, no atomics
    }
}

// ---------------- main kernel: pass 2 only ---------------------------------
__global__ __launch_bounds__(256, 4)
void attn_fused(const float* __restrict__ Q, const bf16* __restrict__ Kimg,
                const bf16* __restrict__ Vimg, const float* __restrict__ Psum,
                float* __restrict__ Rout, float* __restrict__ Pout) {
    const int b = blockIdx.x, qt = blockIdx.y;   // batch-major: XCD = b % 8
    const int tid  = threadIdx.x;
    const int wave = tid >> 6, lane = tid & 63;
    const int n31 = lane & 31, h = lane >> 5;
    const int wn = wave & 1;                     // QK key-half (waves 0,1)

    // LDS: KsB 16KB | VtB 16KB | Ps[32][72] 4.6KB = 37376 B (4 blocks/CU)
    __shared__ __align__(16) char smem[37376];
    char* KsB = smem;
    char* VtB = smem + 16384;
    bf16 (*Ps)[72] = (bf16(*)[72])(smem + 32768);

    const float* Qb = Q + ((size_t)b * SLQ + (size_t)qt * BQ) * DH;
    const char* Kt0 = (const char*)Kimg + (size_t)b * SLK * DH * 2;
    const char* Vt0 = (const char*)Vimg + (size_t)b * SLK * DH * 2;
    float* Rb = Rout + ((size_t)b * SLQ + (size_t)qt * BQ) * DH;
    float* Pb = Pout + ((size_t)b * SLQ + (size_t)qt * BQ) * SLK;

    // stage tile 0 first (latency overlaps aq/rinv loads below)
    {
        const char* ks = Kt0 + wave * 4096 + lane * 16;
        const char* vs = Vt0 + wave * 4096 + lane * 16;
        char* kd = KsB + wave * 4096;
        char* vd = VtB + wave * 4096;
#pragma unroll
        for (int j = 0; j < 4; ++j) {
            gll16(ks + j * 1024, kd + j * 1024);
            gll16(vs + j * 1024, vd + j * 1024);
        }
    }

    // Q B-frags (32 q rows, scale folded): per lane Q[n31][kk*16+8h..+7]
    bf16x8 aq[8];
    {
        const float* qp = Qb + (size_t)n31 * DH + h * 8;
#pragma unroll
        for (int kk = 0; kk < 8; ++kk)
            aq[kk] = cvt8s(*(const f32x4*)(qp + kk * 16),
                           *(const f32x4*)(qp + kk * 16 + 4), SCALE);
    }

    // rinv from prepack partials (32 L2-hot coalesced loads, lane q = n31)
    float rinv;
    {
        const float* pp = Psum + (size_t)b * 32 * SLQ + (size_t)qt * BQ + n31;
        float rs = 0.f;
#pragma unroll
        for (int t = 0; t < 32; ++t) rs += pp[(size_t)t * SLQ];
        rinv = 1.0f / rs;
    }

    asm volatile("s_waitcnt vmcnt(0)" ::: "memory");
    __builtin_amdgcn_s_barrier();                // tile 0 visible
    asm volatile("" ::: "memory");

    f32x16 racc = (f32x16)0.0f;
    const int key2 = wn * 32 + n31;
    const char* kr2 = KsB + key2 * 256;
    const int sw2 = (key2 & 7) << 4;
    const int dpv = wave * 32 + n31;
    const char* vr2 = VtB + dpv * 128;
    const int swv = (dpv & 7) << 4;

    // ---------------- pass 2: P store + PV (BK=64, 32 tiles) ---------------
    for (int kt = 0; kt < 32; ++kt) {
        // QK^T + softmax on waves 0,1 (key-half wn); c col = q (lane)
        if (wave < 2) {
            f32x16 c = (f32x16)0.0f;
#pragma unroll
            for (int kk = 0; kk < 8; ++kk) {
                bf16x8 kf = *(const bf16x8*)(kr2 + ((kk * 32 + 16 * h) ^ sw2));
                c = mfma32(kf, aq[kk], c);
            }
#pragma unroll
            for (int g = 0; g < 4; ++g) {
                bf16x4 pw;
                pw[0] = (bf16)(__expf(c[4 * g + 0]) * rinv);
                pw[1] = (bf16)(__expf(c[4 * g + 1]) * rinv);
                pw[2] = (bf16)(__expf(c[4 * g + 2]) * rinv);
                pw[3] = (bf16)(__expf(c[4 * g + 3]) * rinv);
                *(bf16x4*)&Ps[n31][wn * 32 + 4 * h + 8 * g] = pw;
            }
        }
        barrier_lgkm();   // C: Ps visible to all waves

        // PV: all 4 waves, d = wave*32+n31
#pragma unroll
        for (int kk = 0; kk < 4; ++kk) {
            bf16x8 ap = *(const bf16x8*)&Ps[n31][kk * 16 + 8 * h];
            bf16x8 bv = *(const bf16x8*)(vr2 + (((2 * kk + h) * 16) ^ swv));
            racc = mfma32(ap, bv, racc);
        }
        barrier_lgkm();   // A: all tile-kt Ks/Vt reads done -> restageable

        // stage tile kt+1 (8 glls, zero VGPR)
        if (kt + 1 < 32) {
            const char* ks = Kt0 + (size_t)(kt + 1) * 16384 + wave * 4096 + lane * 16;
            const char* vs = Vt0 + (size_t)(kt + 1) * 16384 + wave * 4096 + lane * 16;
            char* kd = KsB + wave * 4096;
            char* vd = VtB + wave * 4096;
#pragma unroll
            for (int j = 0; j < 4; ++j) {
                gll16(ks + j * 1024, kd + j * 1024);
                gll16(vs + j * 1024, vd + j * 1024);
            }
        }
        asm volatile("" ::: "memory");

        // P store of tile kt (hides gll latency). Lanes 0-7 cover 128B
        // contiguous per instruction -> full-line NT stores.
        {
            int prow = tid >> 3, pc = tid & 7;
            float* dst = Pb + (size_t)prow * SLK + kt * 64;
#pragma unroll
            for (int u = 0; u < 2; ++u) {
                bf16x4 pv = *(const bf16x4*)&Ps[prow][u * 32 + pc * 4];
                f32x4 o;
                o[0] = (float)pv[0]; o[1] = (float)pv[1];
                o[2] = (float)pv[2]; o[3] = (float)pv[3];
                __builtin_nontemporal_store(o, (f32x4*)(dst + u * 32 + pc * 4));
            }
        }
        asm volatile("" ::: "memory");

        // counted wait: queue = [<=2 old stores, 8 glls, 2 new stores];
        // vmcnt(2) -> glls complete, this iter's 2 NT stores stay in flight.
        if (kt + 1 < 32) asm volatile("s_waitcnt vmcnt(2)" ::: "memory");
        __builtin_amdgcn_s_barrier();   // B: staged tile kt+1 visible
        asm volatile("" ::: "memory");
    }

    // epilogue: R store (col = wave*32+n31 = d; row per C-frag reg map)
#pragma unroll
    for (int r = 0; r < 16; ++r) {
        int row = (r & 3) + 8 * (r >> 2) + 4 * h;
        __builtin_nontemporal_store(racc[r], &Rb[(size_t)row * DH + dpv]);
    }
}

extern "C" void kernel_launch(void* const* d_in, const int* in_sizes, int n_in,
                              void* d_out, int out_size, void* d_ws, size_t ws_size,
                              hipStream_t stream) {
    (void)in_sizes; (void)n_in; (void)out_size; (void)ws_size;
    const float* Q = (const float*)d_in[0];
    const float* K = (const float*)d_in[1];
    const float* V = (const float*)d_in[2];
    float* R = (float*)d_out;
    float* P = (float*)d_out + (size_t)NB * SLQ * DH;

    bf16*  Kimg = (bf16*)d_ws;                                   // 8 MB
    bf16*  Vimg = (bf16*)d_ws + (size_t)NB * SLK * DH;           // 8 MB
    float* Psum = (float*)((char*)d_ws + 16777216);              // 4 MB

    prepack<<<dim3(NB, SLK / 64), 256, 0, stream>>>(Q, K, V, Kimg, Vimg, Psum);
    attn_fused<<<dim3(NB, SLQ / BQ), 256, 0, stream>>>(Q, Kimg, Vimg, Psum, R, P);
}